// Round 10
// baseline (513.556 us; speedup 1.0000x reference)
//
#include <hip/hip_runtime.h>
#include <hip/hip_bf16.h>
#include <hip/hip_cooperative_groups.h>

namespace cg = cooperative_groups;

#define NROWS 400000
#define DDIM  512
#define NSEG  50000
#define CAP   64

typedef __bf16 bf16x8 __attribute__((ext_vector_type(8)));
typedef float  f32x4_t __attribute__((ext_vector_type(4)));

#define GLOAD_LDS16(gsrc, ldst)                                                  \
    __builtin_amdgcn_global_load_lds(                                            \
        (const __attribute__((address_space(1))) void*)(gsrc),                   \
        (__attribute__((address_space(3))) void*)(ldst), 16, 0, 0)

// ================= shared phase bodies (used by both paths) =================

__device__ __forceinline__ void transpose_tile_body(int tb, float* tile, int t,
                                                    const float* __restrict__ Wm,
                                                    __bf16* __restrict__ WmT) {
    int kt = tb >> 3, nt = tb & 7;
    int cc = t & 63, rg = t >> 6;
#pragma unroll
    for (int it = 0; it < 16; ++it) {
        int rr = it * 4 + rg;
        tile[rr * 65 + cc] = Wm[(size_t)(kt * 64 + rr) * 512 + nt * 64 + cc];
    }
    __syncthreads();
#pragma unroll
    for (int it = 0; it < 16; ++it) {
        int nn = it * 4 + rg;
        WmT[(size_t)(nt * 64 + nn) * 512 + kt * 64 + cc] = (__bf16)tile[cc * 65 + nn];
    }
    __syncthreads();
}

__device__ __forceinline__ void pool_seg_body(int s, int lane,
                                              const float* __restrict__ x,
                                              const int* __restrict__ counts,
                                              const int* __restrict__ slots,
                                              const f32x4_t wg0, const f32x4_t wg1,
                                              float bg,
                                              __bf16* __restrict__ px,
                                              float* __restrict__ scaleB) {
    const int n = counts[s];
    const int* sid = slots + s * CAP;
    f32x4_t acc0 = {0.f, 0.f, 0.f, 0.f}, acc1 = acc0;
    float gs = 0.f;
    f32x4_t r0a = acc0, r0b = acc0, r1a = acc0, r1b = acc0;
    f32x4_t r2a = acc0, r2b = acc0, r3a = acc0, r3b = acc0;

#define LOADR(k, u0, u1)                                                        \
    {   const float* xr = x + (size_t)sid[k] * DDIM + lane * 8;                 \
        u0 = __builtin_nontemporal_load((const f32x4_t*)xr);                    \
        u1 = __builtin_nontemporal_load((const f32x4_t*)(xr + 4)); }
#define COMPR(u0, u1)                                                           \
    {   float p = u0.x * wg0.x + u0.y * wg0.y + u0.z * wg0.z + u0.w * wg0.w     \
                + u1.x * wg1.x + u1.y * wg1.y + u1.z * wg1.z + u1.w * wg1.w;    \
        p += __shfl_xor(p, 1);  p += __shfl_xor(p, 2);  p += __shfl_xor(p, 4);  \
        p += __shfl_xor(p, 8);  p += __shfl_xor(p, 16); p += __shfl_xor(p, 32); \
        float e = __expf(p + bg);                                               \
        gs += e; acc0 += e * u0; acc1 += e * u1; }

    if (n > 0) LOADR(0, r0a, r0b);
    if (n > 1) LOADR(1, r1a, r1b);
    if (n > 2) LOADR(2, r2a, r2b);
    if (n > 3) LOADR(3, r3a, r3b);
    int k = 0;
    for (; k + 8 <= n; k += 4) {
        COMPR(r0a, r0b); LOADR(k + 4, r0a, r0b);
        COMPR(r1a, r1b); LOADR(k + 5, r1a, r1b);
        COMPR(r2a, r2b); LOADR(k + 6, r2a, r2b);
        COMPR(r3a, r3b); LOADR(k + 7, r3a, r3b);
    }
    {
        int rem = n - k;
        if (rem > 0) COMPR(r0a, r0b);
        if (rem > 4) LOADR(k + 4, r0a, r0b);
        if (rem > 1) COMPR(r1a, r1b);
        if (rem > 5) LOADR(k + 5, r1a, r1b);
        if (rem > 2) COMPR(r2a, r2b);
        if (rem > 6) LOADR(k + 6, r2a, r2b);
        if (rem > 3) COMPR(r3a, r3b);
        if (rem > 4) COMPR(r0a, r0b);
        if (rem > 5) COMPR(r1a, r1b);
        if (rem > 6) COMPR(r2a, r2b);
    }
#undef LOADR
#undef COMPR
    float inv = 1.f / (gs + 1e-10f);
    bf16x8 o;
    o[0] = (__bf16)(acc0.x * inv); o[1] = (__bf16)(acc0.y * inv);
    o[2] = (__bf16)(acc0.z * inv); o[3] = (__bf16)(acc0.w * inv);
    o[4] = (__bf16)(acc1.x * inv); o[5] = (__bf16)(acc1.y * inv);
    o[6] = (__bf16)(acc1.z * inv); o[7] = (__bf16)(acc1.w * inv);
    *(bf16x8*)(px + (size_t)s * DDIM + lane * 8) = o;
    if (lane == 0) scaleB[s] = gs * inv;
}

__device__ __forceinline__ void gemm_tile_body(int mtile, int ntile, int lane, int w,
                                               __bf16* As, __bf16* Bs,
                                               const __bf16* __restrict__ px,
                                               const __bf16* __restrict__ WmT,
                                               const float* __restrict__ bm,
                                               const float* __restrict__ scaleB,
                                               float* __restrict__ out) {
    const int kq = lane & 15;
    const int rq = lane >> 4;
    const int wr = w >> 1;
    const int wc = w & 1;

    const char* srcA[4];
    const char* srcB[4];
    int ldsOff[4];
#pragma unroll
    for (int q = 0; q < 4; ++q) {
        int base = w * 4096 + q * 1024;
        int L = base + lane * 16;
        int r = L >> 7;
        int c = (L & 127) ^ ((r & 7) << 4);
        ldsOff[q] = base;
        int growA = mtile * 128 + r; if (growA >= NSEG) growA = NSEG - 1;
        srcA[q] = (const char*)px + (size_t)growA * 1024 + c;
        srcB[q] = (const char*)WmT + (size_t)(ntile * 128 + r) * 1024 + c;
    }

    f32x4_t acc[4][4];
#pragma unroll
    for (int i = 0; i < 4; ++i)
#pragma unroll
        for (int j = 0; j < 4; ++j)
            acc[i][j] = f32x4_t{0.f, 0.f, 0.f, 0.f};

    for (int ks = 0; ks < 8; ++ks) {
#pragma unroll
        for (int q = 0; q < 4; ++q) {
            GLOAD_LDS16(srcA[q] + ks * 128, (char*)As + ldsOff[q]);
            GLOAD_LDS16(srcB[q] + ks * 128, (char*)Bs + ldsOff[q]);
        }
        asm volatile("s_waitcnt vmcnt(0)" ::: "memory");
        __builtin_amdgcn_s_barrier();
#pragma unroll
        for (int kk = 0; kk < 2; ++kk) {
            int kbyte = rq * 16 + kk * 64;
            bf16x8 a[4], bfr[4];
#pragma unroll
            for (int mi = 0; mi < 4; ++mi) {
                int r = wr * 64 + mi * 16 + kq;
                a[mi] = *(const bf16x8*)((char*)As + ((r * 128 + kbyte) ^ ((r & 7) << 4)));
            }
#pragma unroll
            for (int ni = 0; ni < 4; ++ni) {
                int c = wc * 64 + ni * 16 + kq;
                bfr[ni] = *(const bf16x8*)((char*)Bs + ((c * 128 + kbyte) ^ ((c & 7) << 4)));
            }
#pragma unroll
            for (int mi = 0; mi < 4; ++mi)
#pragma unroll
                for (int ni = 0; ni < 4; ++ni)
                    acc[mi][ni] = __builtin_amdgcn_mfma_f32_16x16x32_bf16(
                        a[mi], bfr[ni], acc[mi][ni], 0, 0, 0);
        }
        __builtin_amdgcn_s_barrier();
    }

#pragma unroll
    for (int mi = 0; mi < 4; ++mi) {
#pragma unroll
        for (int jj = 0; jj < 4; ++jj) {
            int rrow = wr * 64 + mi * 16 + rq * 4 + jj;
            int grow = mtile * 128 + rrow;
            if (grow < NSEG) {
                float sb = scaleB[grow];
                float* op = out + (size_t)grow * DDIM + ntile * 128 + wc * 64 + kq;
                const float* bp = bm + ntile * 128 + wc * 64 + kq;
#pragma unroll
                for (int ni = 0; ni < 4; ++ni)
                    __builtin_nontemporal_store(acc[mi][ni][jj] + bp[ni * 16] * sb,
                                                op + ni * 16);
            }
        }
    }
}

// ================= cooperative fused kernel (grid-size agnostic) =================

__global__ __launch_bounds__(256, 2)
void fused_all(const float* __restrict__ x,
               const int* __restrict__ idx,
               const float* __restrict__ Wg,
               const float* __restrict__ bgp,
               const float* __restrict__ Wm,
               const float* __restrict__ bm,
               int* __restrict__ counts,
               int* __restrict__ slots,
               __bf16* __restrict__ WmT,
               __bf16* __restrict__ px,
               float* __restrict__ scaleB,
               float* __restrict__ out) {
    __shared__ __align__(16) char smem[32768];      // aliased across phases
    float* tile = (float*)smem;
    __bf16* As  = (__bf16*)smem;
    __bf16* Bs  = (__bf16*)(smem + 16384);

    cg::grid_group grid = cg::this_grid();
    const int nb   = gridDim.x;                     // multiple of 8
    const int b    = blockIdx.x;
    const int t    = threadIdx.x;
    const int lane = t & 63;
    const int w    = t >> 6;

    // phase 0: zero counts
    for (int i = b * 256 + t; i < NSEG; i += nb * 256) counts[i] = 0;
    grid.sync();

    // phase 1: slot-scatter + Wm transpose
    for (int wi = b; wi < 1563 + 64; wi += nb) {
        if (wi < 1563) {
            int r = wi * 256 + t;
            if (r < NROWS) {
                int s = idx[r];
                int p = atomicAdd(&counts[s], 1);
                slots[s * CAP + p] = r;
            }
        } else {
            transpose_tile_body(wi - 1563, tile, t, Wm, WmT);
        }
    }
    grid.sync();

    // phase 2: pool
    {
        const f32x4_t wg0 = *(const f32x4_t*)(Wg + lane * 8);
        const f32x4_t wg1 = *(const f32x4_t*)(Wg + lane * 8 + 4);
        const float bg = bgp[0];
        for (int g = b; g < NSEG / 4; g += nb)
            pool_seg_body(g * 4 + w, lane, x, counts, slots, wg0, wg1, bg, px, scaleB);
    }
    grid.sync();

    // phase 3: gemm, XCD-clustered tiles
    {
        const int xk = b & 7;
        const int j  = b >> 3;
        const int nM = (xk < 7) ? 49 : 48;          // mtiles with m%8==xk (391 total)
        const int nT = nM * 4;
        for (int e = j; e < nT; e += (nb >> 3)) {
            gemm_tile_body(xk + 8 * (e >> 2), e & 3, lane, w, As, Bs,
                           px, WmT, bm, scaleB, out);
            __syncthreads();
        }
    }
}

// ================= fallback multi-kernel path (R7 structure) =================

__global__ __launch_bounds__(256)
void scatter_prep(const int* __restrict__ idx, int* __restrict__ counts,
                  int* __restrict__ slots,
                  const float* __restrict__ Wm, __bf16* __restrict__ WmT) {
    __shared__ float tile[64 * 65];
    int b = blockIdx.x;
    int t = threadIdx.x;
    if (b < 1563) {
        int r = b * 256 + t;
        if (r < NROWS) {
            int s = idx[r];
            int p = atomicAdd(&counts[s], 1);
            slots[s * CAP + p] = r;
        }
    } else {
        transpose_tile_body(b - 1563, tile, t, Wm, WmT);
    }
}

__global__ __launch_bounds__(256)
void pool_kernel(const float* __restrict__ x,
                 const int* __restrict__ counts,
                 const int* __restrict__ slots,
                 const float* __restrict__ Wg,
                 const float* __restrict__ bgp,
                 __bf16* __restrict__ px,
                 float* __restrict__ scaleB) {
    const int lane = threadIdx.x & 63;
    const f32x4_t wg0 = *(const f32x4_t*)(Wg + lane * 8);
    const f32x4_t wg1 = *(const f32x4_t*)(Wg + lane * 8 + 4);
    pool_seg_body(blockIdx.x * 4 + (threadIdx.x >> 6), lane, x, counts, slots,
                  wg0, wg1, bgp[0], px, scaleB);
}

__global__ __launch_bounds__(256)
void gemm_out(const __bf16* __restrict__ px,
              const __bf16* __restrict__ WmT,
              const float* __restrict__ bm,
              const float* __restrict__ scaleB,
              float* __restrict__ out) {
    __shared__ __align__(16) __bf16 As[128 * 64];
    __shared__ __align__(16) __bf16 Bs[128 * 64];
    const int xk = blockIdx.x & 7;                  // XCD cluster
    const int j  = blockIdx.x >> 3;                 // 0..195
    const int mtile = xk + 8 * (j >> 2);
    if (mtile >= 391) return;
    gemm_tile_body(mtile, j & 3, threadIdx.x & 63, threadIdx.x >> 6, As, Bs,
                   px, WmT, bm, scaleB, out);
}

extern "C" void kernel_launch(void* const* d_in, const int* in_sizes, int n_in,
                              void* d_out, int out_size, void* d_ws, size_t ws_size,
                              hipStream_t stream) {
    const float* x   = (const float*)d_in[0];
    const int*   idx = (const int*)d_in[1];
    const float* Wg  = (const float*)d_in[2];
    const float* bg  = (const float*)d_in[3];
    const float* Wm  = (const float*)d_in[4];
    const float* bm  = (const float*)d_in[5];
    float* out = (float*)d_out;

    char* W = (char*)d_ws;
    int*    counts = (int*)   (W + 0);            // 200,000 B
    float*  scaleB = (float*) (W + 200704);       // 200,000 B
    __bf16* WmT    = (__bf16*)(W + 401408);       // 524,288 B
    int*    slots  = (int*)   (W + 925696);       // 12,800,000 B
    __bf16* px     = (__bf16*)(W + 13725696);     // 51,200,000 B

    // size the cooperative grid from the runtime's own occupancy model
    int blocksPerCU = 0;
    hipError_t qerr = hipOccupancyMaxActiveBlocksPerMultiprocessor(
        &blocksPerCU, fused_all, 256, 0);
    int nb = 0;
    if (qerr == hipSuccess && blocksPerCU > 0) {
        long cand = (long)blocksPerCU * 256;      // 256 CUs
        if (cand > 1024) cand = 1024;
        nb = (int)(cand & ~7L);                   // multiple of 8
    }

    bool ok = false;
    if (nb >= 8) {
        void* args[] = {(void*)&x, (void*)&idx, (void*)&Wg, (void*)&bg, (void*)&Wm,
                        (void*)&bm, (void*)&counts, (void*)&slots, (void*)&WmT,
                        (void*)&px, (void*)&scaleB, (void*)&out};
        hipError_t lerr = hipLaunchCooperativeKernel((void*)fused_all, dim3(nb),
                                                     dim3(256), args, 0, stream);
        ok = (lerr == hipSuccess);
    }

    if (!ok) {
        // proven multi-kernel chain
        hipMemsetAsync(counts, 0, NSEG * sizeof(int), stream);
        scatter_prep<<<1563 + 64, 256, 0, stream>>>(idx, counts, slots, Wm, WmT);
        pool_kernel<<<NSEG / 4, 256, 0, stream>>>(x, counts, slots, Wg, bg, px, scaleB);
        gemm_out<<<8 * 49 * 4, 256, 0, stream>>>(px, WmT, bm, scaleB, out);
    }
}

// Round 11
// 271.427 us; speedup vs baseline: 1.8921x; 1.8921x over previous
//
#include <hip/hip_runtime.h>
#include <hip/hip_bf16.h>

#define NROWS 400000
#define DDIM  512
#define NSEG  50000
#define CAP   64

typedef __bf16 bf16x8 __attribute__((ext_vector_type(8)));
typedef float  f32x4_t __attribute__((ext_vector_type(4)));

#define GLOAD_LDS16(gsrc, ldst)                                                  \
    __builtin_amdgcn_global_load_lds(                                            \
        (const __attribute__((address_space(1))) void*)(gsrc),                   \
        (__attribute__((address_space(3))) void*)(ldst), 16, 0, 0)

// ---- one pass: slot-scatter (blocks 0..1562) + LDS-tiled Wm transpose ----

__global__ __launch_bounds__(256)
void scatter_prep(const int* __restrict__ idx, int* __restrict__ counts,
                  int* __restrict__ slots,
                  const float* __restrict__ Wm, __bf16* __restrict__ WmT) {
    __shared__ float tile[64 * 65];
    int b = blockIdx.x;
    int t = threadIdx.x;
    if (b < 1563) {
        int r = b * 256 + t;
        if (r < NROWS) {
            int s = idx[r];
            int p = atomicAdd(&counts[s], 1);
            slots[s * CAP + p] = r;
        }
    } else {
        int tb = b - 1563;                 // 0..63 -> 8x8 tiles of 64x64
        int kt = tb >> 3, nt = tb & 7;
        int cc = t & 63, rg = t >> 6;
#pragma unroll
        for (int it = 0; it < 16; ++it) {
            int rr = it * 4 + rg;
            tile[rr * 65 + cc] = Wm[(size_t)(kt * 64 + rr) * 512 + nt * 64 + cc];
        }
        __syncthreads();
#pragma unroll
        for (int it = 0; it < 16; ++it) {
            int nn = it * 4 + rg;
            WmT[(size_t)(nt * 64 + nn) * 512 + kt * 64 + cc] =
                (__bf16)tile[cc * 65 + nn];
        }
    }
}

// ---- pool: one wave per segment, 4 rows in flight ----

__global__ __launch_bounds__(256)
void pool_kernel(const float* __restrict__ x,
                 const int* __restrict__ counts,
                 const int* __restrict__ slots,
                 const float* __restrict__ Wg,
                 const float* __restrict__ bgp,
                 __bf16* __restrict__ px,
                 float* __restrict__ scaleB) {
    const int lane = threadIdx.x & 63;
    const int s = blockIdx.x * 4 + (threadIdx.x >> 6);
    const f32x4_t wg0 = *(const f32x4_t*)(Wg + lane * 8);
    const f32x4_t wg1 = *(const f32x4_t*)(Wg + lane * 8 + 4);
    const float bg = bgp[0];
    const int n   = counts[s];
    const int* sid = slots + s * CAP;

    f32x4_t acc0 = {0.f, 0.f, 0.f, 0.f}, acc1 = acc0;
    float gs = 0.f;

    f32x4_t r0a = acc0, r0b = acc0, r1a = acc0, r1b = acc0;
    f32x4_t r2a = acc0, r2b = acc0, r3a = acc0, r3b = acc0;

#define LOADR(k, u0, u1)                                                        \
    {   const float* xr = x + (size_t)sid[k] * DDIM + lane * 8;                 \
        u0 = __builtin_nontemporal_load((const f32x4_t*)xr);                    \
        u1 = __builtin_nontemporal_load((const f32x4_t*)(xr + 4)); }
#define COMPR(u0, u1)                                                           \
    {   float p = u0.x * wg0.x + u0.y * wg0.y + u0.z * wg0.z + u0.w * wg0.w     \
                + u1.x * wg1.x + u1.y * wg1.y + u1.z * wg1.z + u1.w * wg1.w;    \
        p += __shfl_xor(p, 1);  p += __shfl_xor(p, 2);  p += __shfl_xor(p, 4);  \
        p += __shfl_xor(p, 8);  p += __shfl_xor(p, 16); p += __shfl_xor(p, 32); \
        float e = __expf(p + bg);                                               \
        gs += e; acc0 += e * u0; acc1 += e * u1; }

    if (n > 0) LOADR(0, r0a, r0b);
    if (n > 1) LOADR(1, r1a, r1b);
    if (n > 2) LOADR(2, r2a, r2b);
    if (n > 3) LOADR(3, r3a, r3b);

    int k = 0;
    for (; k + 8 <= n; k += 4) {
        COMPR(r0a, r0b); LOADR(k + 4, r0a, r0b);
        COMPR(r1a, r1b); LOADR(k + 5, r1a, r1b);
        COMPR(r2a, r2b); LOADR(k + 6, r2a, r2b);
        COMPR(r3a, r3b); LOADR(k + 7, r3a, r3b);
    }
    {
        int rem = n - k;                   // 0..7
        if (rem > 0) COMPR(r0a, r0b);
        if (rem > 4) LOADR(k + 4, r0a, r0b);
        if (rem > 1) COMPR(r1a, r1b);
        if (rem > 5) LOADR(k + 5, r1a, r1b);
        if (rem > 2) COMPR(r2a, r2b);
        if (rem > 6) LOADR(k + 6, r2a, r2b);
        if (rem > 3) COMPR(r3a, r3b);
        if (rem > 4) COMPR(r0a, r0b);
        if (rem > 5) COMPR(r1a, r1b);
        if (rem > 6) COMPR(r2a, r2b);
    }
#undef LOADR
#undef COMPR

    float inv = 1.f / (gs + 1e-10f);
    bf16x8 o;
    o[0] = (__bf16)(acc0.x * inv); o[1] = (__bf16)(acc0.y * inv);
    o[2] = (__bf16)(acc0.z * inv); o[3] = (__bf16)(acc0.w * inv);
    o[4] = (__bf16)(acc1.x * inv); o[5] = (__bf16)(acc1.y * inv);
    o[6] = (__bf16)(acc1.z * inv); o[7] = (__bf16)(acc1.w * inv);
    *(bf16x8*)(px + (size_t)s * DDIM + lane * 8) = o;
    if (lane == 0) scaleB[s] = gs * inv;
}

// ---- GEMM: out = px @ Wm + bm*scaleB — m97 structure, XCD-clustered tiles ----

__global__ __launch_bounds__(256)
void gemm_out(const __bf16* __restrict__ px,
              const __bf16* __restrict__ WmT,
              const float* __restrict__ bm,
              const float* __restrict__ scaleB,
              float* __restrict__ out) {
    __shared__ __align__(16) __bf16 As[128 * 64];
    __shared__ __align__(16) __bf16 Bs[128 * 64];

    // XCD-clustered tile order: the 4 ntile-siblings of an mtile land on the
    // same XCD (blocks b, b+8, b+16, b+24 with b%8 fixed) -> px panel L2 reuse.
    const int xk = blockIdx.x & 7;
    const int j  = blockIdx.x >> 3;          // 0..195
    const int mtile = xk + 8 * (j >> 2);
    const int ntile = j & 3;
    if (mtile >= 391) return;

    const int t     = threadIdx.x;
    const int lane  = t & 63;
    const int w     = t >> 6;

    const int kq = lane & 15;
    const int rq = lane >> 4;
    const int wr = w >> 1;
    const int wc = w & 1;

    const char* srcA[4];
    const char* srcB[4];
    int ldsOff[4];
#pragma unroll
    for (int q = 0; q < 4; ++q) {
        int base = w * 4096 + q * 1024;
        int L = base + lane * 16;
        int r = L >> 7;
        int c = (L & 127) ^ ((r & 7) << 4);
        ldsOff[q] = base;
        int growA = mtile * 128 + r; if (growA >= NSEG) growA = NSEG - 1;
        srcA[q] = (const char*)px + (size_t)growA * 1024 + c;
        srcB[q] = (const char*)WmT + (size_t)(ntile * 128 + r) * 1024 + c;
    }

    f32x4_t acc[4][4];
#pragma unroll
    for (int i = 0; i < 4; ++i)
#pragma unroll
        for (int j2 = 0; j2 < 4; ++j2)
            acc[i][j2] = f32x4_t{0.f, 0.f, 0.f, 0.f};

    for (int ks = 0; ks < 8; ++ks) {
#pragma unroll
        for (int q = 0; q < 4; ++q) {
            GLOAD_LDS16(srcA[q] + ks * 128, (char*)As + ldsOff[q]);
            GLOAD_LDS16(srcB[q] + ks * 128, (char*)Bs + ldsOff[q]);
        }
        asm volatile("s_waitcnt vmcnt(0)" ::: "memory");
        __builtin_amdgcn_s_barrier();
#pragma unroll
        for (int kk = 0; kk < 2; ++kk) {
            int kbyte = rq * 16 + kk * 64;
            bf16x8 a[4], b[4];
#pragma unroll
            for (int mi = 0; mi < 4; ++mi) {
                int r = wr * 64 + mi * 16 + kq;
                a[mi] = *(const bf16x8*)((char*)As + ((r * 128 + kbyte) ^ ((r & 7) << 4)));
            }
#pragma unroll
            for (int ni = 0; ni < 4; ++ni) {
                int c = wc * 64 + ni * 16 + kq;
                b[ni] = *(const bf16x8*)((char*)Bs + ((c * 128 + kbyte) ^ ((c & 7) << 4)));
            }
#pragma unroll
            for (int mi = 0; mi < 4; ++mi)
#pragma unroll
                for (int ni = 0; ni < 4; ++ni)
                    acc[mi][ni] = __builtin_amdgcn_mfma_f32_16x16x32_bf16(
                        a[mi], b[ni], acc[mi][ni], 0, 0, 0);
        }
        __builtin_amdgcn_s_barrier();
    }

#pragma unroll
    for (int mi = 0; mi < 4; ++mi) {
#pragma unroll
        for (int jj = 0; jj < 4; ++jj) {
            int rrow = wr * 64 + mi * 16 + rq * 4 + jj;
            int grow = mtile * 128 + rrow;
            if (grow < NSEG) {
                float sb = scaleB[grow];
                float* op = out + (size_t)grow * DDIM + ntile * 128 + wc * 64 + kq;
                const float* bp = bm + ntile * 128 + wc * 64 + kq;
#pragma unroll
                for (int ni = 0; ni < 4; ++ni)
                    __builtin_nontemporal_store(acc[mi][ni][jj] + bp[ni * 16] * sb,
                                                op + ni * 16);
            }
        }
    }
}

extern "C" void kernel_launch(void* const* d_in, const int* in_sizes, int n_in,
                              void* d_out, int out_size, void* d_ws, size_t ws_size,
                              hipStream_t stream) {
    const float* x   = (const float*)d_in[0];
    const int*   idx = (const int*)d_in[1];
    const float* Wg  = (const float*)d_in[2];
    const float* bg  = (const float*)d_in[3];
    const float* Wm  = (const float*)d_in[4];
    const float* bm  = (const float*)d_in[5];
    float* out = (float*)d_out;

    char* W = (char*)d_ws;
    int*    counts = (int*)   (W + 0);            // 200,000 B
    float*  scaleB = (float*) (W + 200704);       // 200,000 B
    __bf16* WmT    = (__bf16*)(W + 401408);       // 524,288 B
    int*    slots  = (int*)   (W + 925696);       // 12,800,000 B
    __bf16* px     = (__bf16*)(W + 13725696);     // 51,200,000 B

    hipMemsetAsync(counts, 0, NSEG * sizeof(int), stream);

    scatter_prep<<<1563 + 64, 256, 0, stream>>>(idx, counts, slots, Wm, WmT);
    pool_kernel<<<NSEG / 4, 256, 0, stream>>>(x, counts, slots, Wg, bg, px, scaleB);

    gemm_out<<<8 * 49 * 4, 256, 0, stream>>>(px, WmT, bm, scaleB, out);
}